// Round 5
// baseline (384.254 us; speedup 1.0000x reference)
//
#include <hip/hip_runtime.h>
#include <stdint.h>

__host__ __device__ inline void tf2x32(uint32_t k0, uint32_t k1,
                                       uint32_t x0, uint32_t x1,
                                       uint32_t* o0, uint32_t* o1) {
  const uint32_t ks2 = k0 ^ k1 ^ 0x1BD11BDAu;
#define ROTL(v, s) (((v) << (s)) | ((v) >> (32 - (s))))
#define RND(r) do { x0 += x1; x1 = ROTL(x1, r); x1 ^= x0; } while (0)
  x0 += k0; x1 += k1;
  RND(13); RND(15); RND(26); RND(6);
  x0 += k1; x1 += ks2 + 1u;
  RND(17); RND(29); RND(16); RND(24);
  x0 += ks2; x1 += k0 + 2u;
  RND(13); RND(15); RND(26); RND(6);
  x0 += k0; x1 += k1 + 3u;
  RND(17); RND(29); RND(16); RND(24);
  x0 += k1; x1 += ks2 + 4u;
  RND(13); RND(15); RND(26); RND(6);
  x0 += ks2; x1 += k0 + 5u;
  *o0 = x0; *o1 = x1;
#undef RND
#undef ROTL
}

__device__ inline bool drop_keep(uint32_t k0, uint32_t k1, uint32_t idx) {
  uint32_t o0, o1;
  tf2x32(k0, k1, 0u, idx, &o0, &o1);
  uint32_t bits = o0 ^ o1;
  float u = __uint_as_float((bits >> 9) | 0x3f800000u) - 1.0f;
  return u < 0.4f;
}

// fp32 -> bf16 with round-to-nearest-even
__device__ inline uint16_t f2bf(float f) {
  uint32_t u = __float_as_uint(f);
  u += 0x7fffu + ((u >> 16) & 1u);
  return (uint16_t)(u >> 16);
}
__device__ inline float bf2f(uint16_t v) {
  return __uint_as_float(((uint32_t)v) << 16);
}

__global__ void k_deg(const int* __restrict__ row, int* __restrict__ deg, int e) {
  int i = blockIdx.x * 256 + threadIdx.x;
  if (i < e) atomicAdd(&deg[row[i]], 1);
}

// single-pass scan over deg (196 blocks) with decoupled lookback.
// st[b]: hi32 flag (0=invalid, 1=aggregate, 2=inclusive-prefix), lo32 value.
__global__ void k_scan_lb(const int* __restrict__ deg, int* __restrict__ rp,
                          unsigned long long* __restrict__ st, int n) {
  __shared__ int sm[256];
  __shared__ int s_excl;
  const int b = blockIdx.x, tid = threadIdx.x;
  const int i = b * 256 + tid;
  int v = (i < n) ? deg[i] : 0;
  sm[tid] = v;
  __syncthreads();
  for (int off = 1; off < 256; off <<= 1) {
    int t = (tid >= off) ? sm[tid - off] : 0;
    __syncthreads();
    sm[tid] += t;
    __syncthreads();
  }
  if (tid == 0) {
    const unsigned long long tot = (unsigned long long)(unsigned)sm[255];
    if (b == 0) {
      __hip_atomic_store(&st[0], (2ULL << 32) | tot, __ATOMIC_RELEASE,
                         __HIP_MEMORY_SCOPE_AGENT);
      s_excl = 0;
    } else {
      __hip_atomic_store(&st[b], (1ULL << 32) | tot, __ATOMIC_RELEASE,
                         __HIP_MEMORY_SCOPE_AGENT);
      int excl = 0;
      int p = b - 1;
      while (true) {
        unsigned long long u = __hip_atomic_load(&st[p], __ATOMIC_ACQUIRE,
                                                 __HIP_MEMORY_SCOPE_AGENT);
        unsigned f = (unsigned)(u >> 32);
        if (f == 0u) continue;          // predecessor not published yet
        excl += (int)(u & 0xffffffffu);
        if (f == 2u) break;
        --p;
      }
      s_excl = excl;
      __hip_atomic_store(&st[b], (2ULL << 32) | (unsigned long long)(unsigned)(excl + sm[255]),
                         __ATOMIC_RELEASE, __HIP_MEMORY_SCOPE_AGENT);
    }
  }
  __syncthreads();
  if (i < n) rp[i + 1] = s_excl + sm[tid];
  if (b == 0 && tid == 0) rp[0] = 0;
}

__global__ void k_fill(const int* __restrict__ row, const int* __restrict__ col,
                       const int* __restrict__ deg, const int* __restrict__ rp,
                       int* __restrict__ cur, int2* __restrict__ cw, int e) {
  int i = blockIdx.x * 256 + threadIdx.x;
  if (i < e) {
    int r = row[i], c = col[i];
    int pos = rp[r] + atomicAdd(&cur[r], 1);
    int dc = deg[c];
    float w = (dc > 0) ? -rsqrtf((float)deg[r]) * rsqrtf((float)dc) : 0.0f;
    cw[pos] = make_int2(c, __float_as_int(w));
  }
}

// layer-0 dropout: fp32 in -> bf16 out
__global__ void k_drop(const float* __restrict__ x, uint16_t* __restrict__ y,
                       uint32_t k0, uint32_t k1, int n) {
  int i = blockIdx.x * 256 + threadIdx.x;
  if (i < n) {
    float v = drop_keep(k0, k1, (uint32_t)i) ? x[i] * 2.5f : 0.0f;
    y[i] = f2bf(v);
  }
}

// Fused conv. Block = 256 threads = 4 waves, R = 16 rows. Input is bf16.
// Phase 1: per-wave CSR gather (8-deep batched) of p = L_hat @ xd; gathered
//   rows are bf16 (128B/row = 2 cache lines); fp32 accumulate; x and p written
//   to xp[r][0:128] (fp32, row-major).
// Phase 2: W-in-registers k-split MLP (thread (kc,o) holds CH W values).
// Phase 3: reduce partials + bias + relu + next-layer dropout; store bf16
//   (inter-layer) or fp32 (final output).
template<int COUT, bool RELU, bool DROPN, bool WBF>
__global__ __launch_bounds__(256, 4) void k_conv(
    const uint16_t* __restrict__ xg, const int* __restrict__ rp,
    const int2* __restrict__ cw, const float* __restrict__ W,
    const float* __restrict__ b, float* __restrict__ outf,
    uint16_t* __restrict__ outb, uint32_t nk0, uint32_t nk1, int n) {
  constexpr int R  = 16;
  constexpr int KC = (COUT == 64) ? 4 : 8;
  constexpr int CH = 128 / KC;
  constexpr int TS = 132;
  __shared__ __align__(16) float xp[R][TS];
  __shared__ float partial[R * KC * COUT];

  const int wave = threadIdx.x >> 6;
  const int t    = threadIdx.x & 63;
  const int row0 = blockIdx.x * R;

  const int kc = threadIdx.x / COUT;
  const int o  = threadIdx.x % COUT;
  float Wreg[CH];
  #pragma unroll
  for (int j = 0; j < CH; ++j) Wreg[j] = W[(kc * CH + j) * COUT + o];

  // ---- Phase 1: gather (8-deep batched, bf16 rows) ----
  for (int i = 0; i < 4; ++i) {
    const int rl = wave * 4 + i;
    const int r  = row0 + rl;
    if (r < n) {
      float xv0 = bf2f(xg[(size_t)r * 64 + t]);
      float acc = 0.0f;
      const int ee0 = rp[r];
      const int e1  = rp[r + 1];
      for (int ee = ee0; ee < e1; ee += 8) {
        int   c[8];
        float w[8];
        #pragma unroll
        for (int j = 0; j < 8; ++j) {
          int idx = ee + j;
          int2 v = cw[idx < e1 ? idx : ee0];   // row nonempty here
          c[j] = v.x;
          w[j] = (idx < e1) ? __int_as_float(v.y) : 0.0f;
        }
        uint16_t xv[8];
        #pragma unroll
        for (int j = 0; j < 8; ++j) xv[j] = xg[(size_t)c[j] * 64 + t];
        #pragma unroll
        for (int j = 0; j < 8; ++j) acc = fmaf(w[j], bf2f(xv[j]), acc);
      }
      xp[rl][t]      = xv0;
      xp[rl][64 + t] = acc;
    }
  }
  __syncthreads();

  // ---- Phase 2: per-row partial dot (broadcast float4 reads, reg W) ----
  #pragma unroll 4
  for (int rl = 0; rl < R; ++rl) {
    float a = 0.0f;
    #pragma unroll
    for (int j4 = 0; j4 < CH; j4 += 4) {
      const float4 xv = *reinterpret_cast<const float4*>(&xp[rl][kc * CH + j4]);
      a = fmaf(xv.x, Wreg[j4 + 0], a);
      a = fmaf(xv.y, Wreg[j4 + 1], a);
      a = fmaf(xv.z, Wreg[j4 + 2], a);
      a = fmaf(xv.w, Wreg[j4 + 3], a);
    }
    partial[(rl * KC + kc) * COUT + o] = a;
  }
  __syncthreads();

  // ---- Phase 3: reduce + epilogue ----
  for (int i = threadIdx.x; i < R * COUT; i += 256) {
    const int rl = i / COUT;
    const int oo = i % COUT;
    const int rr = row0 + rl;
    if (rr < n) {
      float v = b[oo];
      #pragma unroll
      for (int k = 0; k < KC; ++k) v += partial[(rl * KC + k) * COUT + oo];
      if (RELU) v = fmaxf(v, 0.0f);
      if (DROPN) {
        if (drop_keep(nk0, nk1, (uint32_t)(rr * 64 + oo))) v *= 2.5f;
        else v = 0.0f;
      }
      if (WBF) outb[(size_t)rr * COUT + oo] = f2bf(v);
      else     outf[(size_t)rr * COUT + oo] = v;
    }
  }
}

extern "C" void kernel_launch(void* const* d_in, const int* in_sizes, int n_in,
                              void* d_out, int out_size, void* d_ws, size_t ws_size,
                              hipStream_t stream) {
  const float* x   = (const float*)d_in[0];
  const int*   ei  = (const int*)d_in[1];
  const float* W0  = (const float*)d_in[2];
  const float* b0  = (const float*)d_in[3];
  const float* W1f = (const float*)d_in[4];
  const float* b1  = (const float*)d_in[5];
  const float* W2  = (const float*)d_in[6];
  const float* b2  = (const float*)d_in[7];
  float* out = (float*)d_out;

  const int n = in_sizes[0] / 64;   // 50000
  const int e = in_sizes[1] / 2;    // 800000
  const int* row = ei;
  const int* col = ei + e;

  size_t off = 0;
  auto carve = [&](size_t elems) {
    size_t o = off;
    off += (elems + 255) & ~(size_t)255;
    return o;
  };
  int* base = (int*)d_ws;
  // deg, cur, st contiguous -> single memset
  int*      deg = base + carve(n);
  int*      cur = base + carve(n);
  unsigned long long* st = (unsigned long long*)(base + carve(2 * 256));
  const size_t zero_ints = carve(0);   // end of zeroed region
  int*      rp  = base + carve((size_t)n + 1);
  int2*     cw  = (int2*)(base + carve((size_t)e * 2));
  uint16_t* xab = (uint16_t*)(base + carve((size_t)n * 32));  // n*64 bf16
  uint16_t* xbb = (uint16_t*)(base + carve((size_t)n * 32));
  (void)ws_size;

  // dropout keys: fold_in(jax.random.key(1), i) = threefry2x32([0,1],[0,i])
  uint32_t dk[3][2];
  for (uint32_t i = 0; i < 3; ++i) tf2x32(0u, 1u, 0u, i, &dk[i][0], &dk[i][1]);

  hipMemsetAsync(deg, 0, zero_ints * 4, stream);

  const int be = (e + 255) / 256;
  const int bn = (n + 255) / 256;     // 196
  const int bd = ((n * 64) + 255) / 256;
  const int bc = (n + 15) / 16;       // 3125 blocks, 16 rows each

  k_deg<<<be, 256, 0, stream>>>(row, deg, e);
  k_scan_lb<<<bn, 256, 0, stream>>>(deg, rp, st, n);
  k_fill<<<be, 256, 0, stream>>>(row, col, deg, rp, cur, cw, e);

  k_drop<<<bd, 256, 0, stream>>>(x, xab, dk[0][0], dk[0][1], n * 64);
  k_conv<64, true,  true,  true ><<<bc, 256, 0, stream>>>(xab, rp, cw, W0,  b0, nullptr, xbb, dk[1][0], dk[1][1], n);
  k_conv<64, true,  true,  true ><<<bc, 256, 0, stream>>>(xbb, rp, cw, W1f, b1, nullptr, xab, dk[2][0], dk[2][1], n);
  k_conv<32, false, false, false><<<bc, 256, 0, stream>>>(xab, rp, cw, W2,  b2, out, nullptr, 0u, 0u, n);
}

// Round 6
// 293.868 us; speedup vs baseline: 1.3076x; 1.3076x over previous
//
#include <hip/hip_runtime.h>
#include <stdint.h>

typedef _Float16 half8 __attribute__((ext_vector_type(8)));
typedef float float4v __attribute__((ext_vector_type(4)));

__host__ __device__ inline void tf2x32(uint32_t k0, uint32_t k1,
                                       uint32_t x0, uint32_t x1,
                                       uint32_t* o0, uint32_t* o1) {
  const uint32_t ks2 = k0 ^ k1 ^ 0x1BD11BDAu;
#define ROTL(v, s) (((v) << (s)) | ((v) >> (32 - (s))))
#define RND(r) do { x0 += x1; x1 = ROTL(x1, r); x1 ^= x0; } while (0)
  x0 += k0; x1 += k1;
  RND(13); RND(15); RND(26); RND(6);
  x0 += k1; x1 += ks2 + 1u;
  RND(17); RND(29); RND(16); RND(24);
  x0 += ks2; x1 += k0 + 2u;
  RND(13); RND(15); RND(26); RND(6);
  x0 += k0; x1 += k1 + 3u;
  RND(17); RND(29); RND(16); RND(24);
  x0 += k1; x1 += ks2 + 4u;
  RND(13); RND(15); RND(26); RND(6);
  x0 += ks2; x1 += k0 + 5u;
  *o0 = x0; *o1 = x1;
#undef RND
#undef ROTL
}

__device__ inline bool drop_keep(uint32_t k0, uint32_t k1, uint32_t idx) {
  uint32_t o0, o1;
  tf2x32(k0, k1, 0u, idx, &o0, &o1);
  uint32_t bits = o0 ^ o1;
  float u = __uint_as_float((bits >> 9) | 0x3f800000u) - 1.0f;
  return u < 0.4f;
}

__global__ void k_deg(const int* __restrict__ row, int* __restrict__ deg, int e) {
  int i = blockIdx.x * 256 + threadIdx.x;
  if (i < e) atomicAdd(&deg[row[i]], 1);
}

__global__ void k_scan_block(const int* __restrict__ deg, int* __restrict__ rp,
                             int* __restrict__ blksum, int n) {
  __shared__ int sm[256];
  int i = blockIdx.x * 256 + threadIdx.x;
  int v = (i < n) ? deg[i] : 0;
  sm[threadIdx.x] = v;
  __syncthreads();
  for (int off = 1; off < 256; off <<= 1) {
    int t = (threadIdx.x >= off) ? sm[threadIdx.x - off] : 0;
    __syncthreads();
    sm[threadIdx.x] += t;
    __syncthreads();
  }
  if (i < n) rp[i + 1] = sm[threadIdx.x];
  if (threadIdx.x == 255) blksum[blockIdx.x] = sm[255];
}

__global__ void k_scan_top(int* __restrict__ blk, int nblk) {
  __shared__ int sm[256];
  int v = (threadIdx.x < nblk) ? blk[threadIdx.x] : 0;
  sm[threadIdx.x] = v;
  __syncthreads();
  for (int off = 1; off < 256; off <<= 1) {
    int t = (threadIdx.x >= off) ? sm[threadIdx.x - off] : 0;
    __syncthreads();
    sm[threadIdx.x] += t;
    __syncthreads();
  }
  if (threadIdx.x < nblk) blk[threadIdx.x] = sm[threadIdx.x] - v;
}

__global__ void k_scan_add(int* __restrict__ rp, const int* __restrict__ blk, int n) {
  int i = blockIdx.x * 256 + threadIdx.x;
  if (i == 0) rp[0] = 0;
  if (i < n) rp[i + 1] += blk[i >> 8];
}

__global__ void k_fill(const int* __restrict__ row, const int* __restrict__ col,
                       const int* __restrict__ deg, const int* __restrict__ rp,
                       int* __restrict__ cur, int2* __restrict__ cw, int e) {
  int i = blockIdx.x * 256 + threadIdx.x;
  if (i < e) {
    int r = row[i], c = col[i];
    int pos = rp[r] + atomicAdd(&cur[r], 1);
    int dc = deg[c];
    float w = (dc > 0) ? -rsqrtf((float)deg[r]) * rsqrtf((float)dc) : 0.0f;
    cw[pos] = make_int2(c, __float_as_int(w));
  }
}

// layer-0 dropout: fp32 in -> f16 out
__global__ void k_drop(const float* __restrict__ x, _Float16* __restrict__ y,
                       uint32_t k0, uint32_t k1, int n) {
  int i = blockIdx.x * 256 + threadIdx.x;
  if (i < n) {
    float v = drop_keep(k0, k1, (uint32_t)i) ? x[i] * 2.5f : 0.0f;
    y[i] = (_Float16)v;
  }
}

// Fused conv. Block = 256 threads = 4 waves, R = 16 rows. Activations f16.
// Phase 0: stage W^T (f16) into LDS.
// Phase 1: per-wave CSR gather of p = L_hat @ x (full 8-batches unmasked +
//          masked tail), fp32 accumulate; write x|p as f16 tile xp[16][128].
// Phase 2: MFMA 16x16x32_f16: wave w computes out cols 16w..16w+15;
//          4 K-steps over K=128. A[m=lane&15][k=quad*8+j] from xp,
//          B = W^T[n=lane&15][k] from Wt. D: col=lane&15, row=quad*4+reg.
// Phase 3: epilogue per lane: +bias, relu, next-layer dropout, store.
template<int COUT, bool RELU, bool DROPN, bool WBF>
__global__ __launch_bounds__(256, 4) void k_conv(
    const _Float16* __restrict__ xg, const int* __restrict__ rp,
    const int2* __restrict__ cw, const float* __restrict__ W,
    const float* __restrict__ b, float* __restrict__ outf,
    _Float16* __restrict__ outb, uint32_t nk0, uint32_t nk1, int n) {
  constexpr int R  = 16;
  constexpr int TS = 136;                     // padded K stride (16B-aligned)
  __shared__ __align__(16) _Float16 xp[R][TS];
  __shared__ __align__(16) _Float16 Wt[COUT][TS];

  const int wave = threadIdx.x >> 6;
  const int t    = threadIdx.x & 63;
  const int row0 = blockIdx.x * R;

  // ---- Phase 0: stage W^T as f16 ----
  for (int i = threadIdx.x; i < 128 * COUT; i += 256) {
    const int k = i / COUT, o = i % COUT;
    Wt[o][k] = (_Float16)W[i];
  }

  // ---- Phase 1: gather ----
  for (int i = 0; i < 4; ++i) {
    const int rl = wave * 4 + i;
    const int r  = row0 + rl;
    if (r < n) {
      float acc = 0.0f;
      int       ee = rp[r];
      const int e1 = rp[r + 1];
      const int ee0 = ee;
      for (; ee + 8 <= e1; ee += 8) {          // full batches: no masking
        int   c[8];
        float w[8];
        #pragma unroll
        for (int j = 0; j < 8; ++j) {
          int2 v = cw[ee + j];
          c[j] = v.x;
          w[j] = __int_as_float(v.y);
        }
        _Float16 xv[8];
        #pragma unroll
        for (int j = 0; j < 8; ++j) xv[j] = xg[(uint32_t)(c[j] << 6) + t];
        #pragma unroll
        for (int j = 0; j < 8; ++j) acc = fmaf(w[j], (float)xv[j], acc);
      }
      if (ee < e1) {                           // masked tail (<8 edges)
        int   c[8];
        float w[8];
        #pragma unroll
        for (int j = 0; j < 8; ++j) {
          int idx = ee + j;
          int2 v = cw[idx < e1 ? idx : ee0];
          c[j] = v.x;
          w[j] = (idx < e1) ? __int_as_float(v.y) : 0.0f;
        }
        _Float16 xv[8];
        #pragma unroll
        for (int j = 0; j < 8; ++j) xv[j] = xg[(uint32_t)(c[j] << 6) + t];
        #pragma unroll
        for (int j = 0; j < 8; ++j) acc = fmaf(w[j], (float)xv[j], acc);
      }
      xp[rl][t]      = xg[(uint32_t)(r << 6) + t];
      xp[rl][64 + t] = (_Float16)acc;
    }
  }
  __syncthreads();

  // ---- Phase 2: MFMA ----
  constexpr int NW = COUT / 16;                // N-tiles (4 or 2)
  const int nn   = t & 15;
  const int quad = t >> 4;
  if (wave < NW) {
    float4v acc = {0.f, 0.f, 0.f, 0.f};
    #pragma unroll
    for (int ks = 0; ks < 4; ++ks) {
      half8 a  = *(const half8*)&xp[nn][quad * 8 + 32 * ks];
      half8 bb = *(const half8*)&Wt[wave * 16 + nn][quad * 8 + 32 * ks];
      acc = __builtin_amdgcn_mfma_f32_16x16x32_f16(a, bb, acc, 0, 0, 0);
    }
    // ---- Phase 3: epilogue ----
    const int colg = wave * 16 + nn;
    const float bias = b[colg];
    #pragma unroll
    for (int rg = 0; rg < 4; ++rg) {
      const int rl = quad * 4 + rg;
      const int rr = row0 + rl;
      if (rr < n) {
        float v = acc[rg] + bias;
        if (RELU) v = fmaxf(v, 0.0f);
        if (DROPN) {
          if (drop_keep(nk0, nk1, (uint32_t)(rr * 64 + colg))) v *= 2.5f;
          else v = 0.0f;
        }
        if (WBF) outb[(size_t)rr * COUT + colg] = (_Float16)v;
        else     outf[(size_t)rr * COUT + colg] = v;
      }
    }
  }
}

extern "C" void kernel_launch(void* const* d_in, const int* in_sizes, int n_in,
                              void* d_out, int out_size, void* d_ws, size_t ws_size,
                              hipStream_t stream) {
  const float* x   = (const float*)d_in[0];
  const int*   ei  = (const int*)d_in[1];
  const float* W0  = (const float*)d_in[2];
  const float* b0  = (const float*)d_in[3];
  const float* W1f = (const float*)d_in[4];
  const float* b1  = (const float*)d_in[5];
  const float* W2  = (const float*)d_in[6];
  const float* b2  = (const float*)d_in[7];
  float* out = (float*)d_out;

  const int n = in_sizes[0] / 64;   // 50000
  const int e = in_sizes[1] / 2;    // 800000
  const int* row = ei;
  const int* col = ei + e;

  size_t off = 0;
  auto carve = [&](size_t elems) {
    size_t o = off;
    off += (elems + 255) & ~(size_t)255;
    return o;
  };
  int* base = (int*)d_ws;
  // deg, cur contiguous -> single memset
  int*      deg = base + carve(n);
  int*      cur = base + carve(n);
  const size_t zero_ints = carve(0);
  int*      rp  = base + carve((size_t)n + 1);
  int*      blk = base + carve(256);
  int2*     cw  = (int2*)(base + carve((size_t)e * 2));
  _Float16* xah = (_Float16*)(base + carve((size_t)n * 32));  // n*64 f16
  _Float16* xbh = (_Float16*)(base + carve((size_t)n * 32));
  (void)ws_size;

  // dropout keys: fold_in(jax.random.key(1), i) = threefry2x32([0,1],[0,i])
  uint32_t dk[3][2];
  for (uint32_t i = 0; i < 3; ++i) tf2x32(0u, 1u, 0u, i, &dk[i][0], &dk[i][1]);

  hipMemsetAsync(deg, 0, zero_ints * 4, stream);

  const int be = (e + 255) / 256;
  const int bn = (n + 255) / 256;     // 196
  const int bd = ((n * 64) + 255) / 256;
  const int bc = (n + 15) / 16;       // 3125 blocks, 16 rows each

  k_deg<<<be, 256, 0, stream>>>(row, deg, e);
  k_scan_block<<<bn, 256, 0, stream>>>(deg, rp, blk, n);
  k_scan_top<<<1, 256, 0, stream>>>(blk, bn);
  k_scan_add<<<bn, 256, 0, stream>>>(rp, blk, n);
  k_fill<<<be, 256, 0, stream>>>(row, col, deg, rp, cur, cw, e);

  k_drop<<<bd, 256, 0, stream>>>(x, xah, dk[0][0], dk[0][1], n * 64);
  k_conv<64, true,  true,  true ><<<bc, 256, 0, stream>>>(xah, rp, cw, W0,  b0, nullptr, xbh, dk[1][0], dk[1][1], n);
  k_conv<64, true,  true,  true ><<<bc, 256, 0, stream>>>(xbh, rp, cw, W1f, b1, nullptr, xah, dk[2][0], dk[2][1], n);
  k_conv<32, false, false, false><<<bc, 256, 0, stream>>>(xah, rp, cw, W2,  b2, out, nullptr, 0u, 0u, n);
}

// Round 7
// 290.425 us; speedup vs baseline: 1.3231x; 1.0119x over previous
//
#include <hip/hip_runtime.h>
#include <stdint.h>

typedef _Float16 half8 __attribute__((ext_vector_type(8)));
typedef float float4v __attribute__((ext_vector_type(4)));

__host__ __device__ inline void tf2x32(uint32_t k0, uint32_t k1,
                                       uint32_t x0, uint32_t x1,
                                       uint32_t* o0, uint32_t* o1) {
  const uint32_t ks2 = k0 ^ k1 ^ 0x1BD11BDAu;
#define ROTL(v, s) (((v) << (s)) | ((v) >> (32 - (s))))
#define RND(r) do { x0 += x1; x1 = ROTL(x1, r); x1 ^= x0; } while (0)
  x0 += k0; x1 += k1;
  RND(13); RND(15); RND(26); RND(6);
  x0 += k1; x1 += ks2 + 1u;
  RND(17); RND(29); RND(16); RND(24);
  x0 += ks2; x1 += k0 + 2u;
  RND(13); RND(15); RND(26); RND(6);
  x0 += k0; x1 += k1 + 3u;
  RND(17); RND(29); RND(16); RND(24);
  x0 += k1; x1 += ks2 + 4u;
  RND(13); RND(15); RND(26); RND(6);
  x0 += ks2; x1 += k0 + 5u;
  *o0 = x0; *o1 = x1;
#undef RND
#undef ROTL
}

__device__ inline bool drop_keep(uint32_t k0, uint32_t k1, uint32_t idx) {
  uint32_t o0, o1;
  tf2x32(k0, k1, 0u, idx, &o0, &o1);
  uint32_t bits = o0 ^ o1;
  float u = __uint_as_float((bits >> 9) | 0x3f800000u) - 1.0f;
  return u < 0.4f;
}

// k_deg: edge-degree atomics; first 80 blocks ALSO convert W0/W1/W2 to f16
// transposed layout wh[o][k] (independent work, saves a launch).
__global__ void k_deg(const int* __restrict__ row, int* __restrict__ deg, int e,
                      const float* __restrict__ W0, const float* __restrict__ W1,
                      const float* __restrict__ W2, _Float16* __restrict__ wh) {
  int i = blockIdx.x * 256 + threadIdx.x;
  if (blockIdx.x < 80) {
    int d = i;                       // 0..20479
    if (d < 8192) {
      int o = d >> 7, k = d & 127;
      wh[d] = (_Float16)W0[k * 64 + o];
    } else if (d < 16384) {
      int d1 = d - 8192, o = d1 >> 7, k = d1 & 127;
      wh[d] = (_Float16)W1[k * 64 + o];
    } else if (d < 20480) {
      int d2 = d - 16384, o = d2 >> 7, k = d2 & 127;
      wh[d] = (_Float16)W2[k * 32 + o];
    }
  }
  if (i < e) atomicAdd(&deg[row[i]], 1);
}

__global__ void k_scan_block(const int* __restrict__ deg, int* __restrict__ rp,
                             int* __restrict__ blksum, int n) {
  __shared__ int sm[256];
  int i = blockIdx.x * 256 + threadIdx.x;
  int v = (i < n) ? deg[i] : 0;
  sm[threadIdx.x] = v;
  __syncthreads();
  for (int off = 1; off < 256; off <<= 1) {
    int t = (threadIdx.x >= off) ? sm[threadIdx.x - off] : 0;
    __syncthreads();
    sm[threadIdx.x] += t;
    __syncthreads();
  }
  if (i < n) rp[i + 1] = sm[threadIdx.x];
  if (threadIdx.x == 255) blksum[blockIdx.x] = sm[255];
}

__global__ void k_scan_top(int* __restrict__ blk, int nblk) {
  __shared__ int sm[256];
  int v = (threadIdx.x < nblk) ? blk[threadIdx.x] : 0;
  sm[threadIdx.x] = v;
  __syncthreads();
  for (int off = 1; off < 256; off <<= 1) {
    int t = (threadIdx.x >= off) ? sm[threadIdx.x - off] : 0;
    __syncthreads();
    sm[threadIdx.x] += t;
    __syncthreads();
  }
  if (threadIdx.x < nblk) blk[threadIdx.x] = sm[threadIdx.x] - v;
}

// also zeroes cur[] (removes half the memset)
__global__ void k_scan_add(int* __restrict__ rp, const int* __restrict__ blk,
                           int* __restrict__ cur, int n) {
  int i = blockIdx.x * 256 + threadIdx.x;
  if (i == 0) rp[0] = 0;
  if (i < n) {
    rp[i + 1] += blk[i >> 8];
    cur[i] = 0;
  }
}

// fused: CSR fill (i < e) + layer-0 dropout fp32->f16 (i < n*64).
// grid sized for the larger (n*64).
__global__ void k_fill_drop(const int* __restrict__ row, const int* __restrict__ col,
                            const int* __restrict__ deg, const int* __restrict__ rp,
                            int* __restrict__ cur, int2* __restrict__ cw, int e,
                            const float* __restrict__ x, _Float16* __restrict__ y,
                            uint32_t k0, uint32_t k1, int nd) {
  int i = blockIdx.x * 256 + threadIdx.x;
  if (i < e) {
    int r = row[i], c = col[i];
    int pos = rp[r] + atomicAdd(&cur[r], 1);
    int dc = deg[c];
    float w = (dc > 0) ? -rsqrtf((float)deg[r]) * rsqrtf((float)dc) : 0.0f;
    cw[pos] = make_int2(c, __float_as_int(w));
  }
  if (i < nd) {
    float v = drop_keep(k0, k1, (uint32_t)i) ? x[i] * 2.5f : 0.0f;
    y[i] = (_Float16)v;
  }
}

// Fused conv. Block = 256 threads = 4 waves, R = 16 rows. Activations f16.
// Phase 1: per-wave CSR gather of p = L_hat @ x (full 8-batches unmasked +
//          masked tail), fp32 accumulate; write x|p as f16 tile xp[16][136].
// Phase 2: MFMA 16x16x32_f16, 4 K-steps. A from xp (LDS); B fragments loaded
//          DIRECTLY from global f16 W^T (16KB, L1-resident across blocks).
// Phase 3: epilogue: +bias, relu, next-layer dropout, store.
// LDS = xp only (~4.4KB) -> high occupancy; launch_bounds(256,8).
template<int COUT, bool RELU, bool DROPN, bool WBF>
__global__ __launch_bounds__(256, 8) void k_conv(
    const _Float16* __restrict__ xg, const int* __restrict__ rp,
    const int2* __restrict__ cw, const _Float16* __restrict__ wt,
    const float* __restrict__ b, float* __restrict__ outf,
    _Float16* __restrict__ outb, uint32_t nk0, uint32_t nk1, int n) {
  constexpr int R  = 16;
  constexpr int TS = 136;
  __shared__ __align__(16) _Float16 xp[R][TS];

  const int wave = threadIdx.x >> 6;
  const int t    = threadIdx.x & 63;
  const int row0 = blockIdx.x * R;

  // ---- Phase 1: gather ----
  for (int i = 0; i < 4; ++i) {
    const int rl = wave * 4 + i;
    const int r  = row0 + rl;
    if (r < n) {
      float acc = 0.0f;
      int       ee = rp[r];
      const int e1 = rp[r + 1];
      const int ee0 = ee;
      for (; ee + 8 <= e1; ee += 8) {          // full batches: no masking
        int   c[8];
        float w[8];
        #pragma unroll
        for (int j = 0; j < 8; ++j) {
          int2 v = cw[ee + j];
          c[j] = v.x;
          w[j] = __int_as_float(v.y);
        }
        _Float16 xv[8];
        #pragma unroll
        for (int j = 0; j < 8; ++j) xv[j] = xg[(uint32_t)(c[j] << 6) + t];
        #pragma unroll
        for (int j = 0; j < 8; ++j) acc = fmaf(w[j], (float)xv[j], acc);
      }
      if (ee < e1) {                           // masked tail (<8 edges)
        int   c[8];
        float w[8];
        #pragma unroll
        for (int j = 0; j < 8; ++j) {
          int idx = ee + j;
          int2 v = cw[idx < e1 ? idx : ee0];
          c[j] = v.x;
          w[j] = (idx < e1) ? __int_as_float(v.y) : 0.0f;
        }
        _Float16 xv[8];
        #pragma unroll
        for (int j = 0; j < 8; ++j) xv[j] = xg[(uint32_t)(c[j] << 6) + t];
        #pragma unroll
        for (int j = 0; j < 8; ++j) acc = fmaf(w[j], (float)xv[j], acc);
      }
      xp[rl][t]      = xg[(uint32_t)(r << 6) + t];
      xp[rl][64 + t] = (_Float16)acc;
    }
  }
  __syncthreads();

  // ---- Phase 2: MFMA (B fragments from global W^T) ----
  constexpr int NW = COUT / 16;                // N-tiles (4 or 2)
  const int nn   = t & 15;
  const int quad = t >> 4;
  if (wave < NW) {
    const int colg = wave * 16 + nn;
    float4v acc = {0.f, 0.f, 0.f, 0.f};
    #pragma unroll
    for (int ks = 0; ks < 4; ++ks) {
      half8 a  = *(const half8*)&xp[nn][quad * 8 + 32 * ks];
      half8 bb = *(const half8*)&wt[(size_t)colg * 128 + quad * 8 + 32 * ks];
      acc = __builtin_amdgcn_mfma_f32_16x16x32_f16(a, bb, acc, 0, 0, 0);
    }
    // ---- Phase 3: epilogue ----
    const float bias = b[colg];
    #pragma unroll
    for (int rg = 0; rg < 4; ++rg) {
      const int rl = quad * 4 + rg;
      const int rr = row0 + rl;
      if (rr < n) {
        float v = acc[rg] + bias;
        if (RELU) v = fmaxf(v, 0.0f);
        if (DROPN) {
          if (drop_keep(nk0, nk1, (uint32_t)(rr * 64 + colg))) v *= 2.5f;
          else v = 0.0f;
        }
        if (WBF) outb[(size_t)rr * COUT + colg] = (_Float16)v;
        else     outf[(size_t)rr * COUT + colg] = v;
      }
    }
  }
}

extern "C" void kernel_launch(void* const* d_in, const int* in_sizes, int n_in,
                              void* d_out, int out_size, void* d_ws, size_t ws_size,
                              hipStream_t stream) {
  const float* x   = (const float*)d_in[0];
  const int*   ei  = (const int*)d_in[1];
  const float* W0  = (const float*)d_in[2];
  const float* b0  = (const float*)d_in[3];
  const float* W1f = (const float*)d_in[4];
  const float* b1  = (const float*)d_in[5];
  const float* W2  = (const float*)d_in[6];
  const float* b2  = (const float*)d_in[7];
  float* out = (float*)d_out;

  const int n = in_sizes[0] / 64;   // 50000
  const int e = in_sizes[1] / 2;    // 800000
  const int* row = ei;
  const int* col = ei + e;

  size_t off = 0;
  auto carve = [&](size_t elems) {
    size_t o = off;
    off += (elems + 255) & ~(size_t)255;
    return o;
  };
  int* base = (int*)d_ws;
  int*      deg = base + carve(n);
  int*      cur = base + carve(n);
  int*      rp  = base + carve((size_t)n + 1);
  int*      blk = base + carve(256);
  int2*     cw  = (int2*)(base + carve((size_t)e * 2));
  _Float16* xah = (_Float16*)(base + carve((size_t)n * 32));  // n*64 f16
  _Float16* xbh = (_Float16*)(base + carve((size_t)n * 32));
  _Float16* wh  = (_Float16*)(base + carve(10240));           // 20480 f16
  (void)ws_size;
  _Float16* wh0 = wh;            // [64][128]
  _Float16* wh1 = wh + 8192;     // [64][128]
  _Float16* wh2 = wh + 16384;    // [32][128]

  // dropout keys: fold_in(jax.random.key(1), i) = threefry2x32([0,1],[0,i])
  uint32_t dk[3][2];
  for (uint32_t i = 0; i < 3; ++i) tf2x32(0u, 1u, 0u, i, &dk[i][0], &dk[i][1]);

  hipMemsetAsync(deg, 0, (size_t)n * 4, stream);

  const int be = (e + 255) / 256;       // 3125
  const int bn = (n + 255) / 256;       // 196
  const int bd = ((n * 64) + 255) / 256; // 12500
  const int bc = (n + 15) / 16;         // 3125

  k_deg<<<be, 256, 0, stream>>>(row, deg, e, W0, W1f, W2, wh);
  k_scan_block<<<bn, 256, 0, stream>>>(deg, rp, blk, n);
  k_scan_top<<<1, 256, 0, stream>>>(blk, bn);
  k_scan_add<<<bn, 256, 0, stream>>>(rp, blk, cur, n);
  k_fill_drop<<<bd, 256, 0, stream>>>(row, col, deg, rp, cur, cw, e,
                                      x, xah, dk[0][0], dk[0][1], n * 64);

  k_conv<64, true,  true,  true ><<<bc, 256, 0, stream>>>(xah, rp, cw, wh0, b0, nullptr, xbh, dk[1][0], dk[1][1], n);
  k_conv<64, true,  true,  true ><<<bc, 256, 0, stream>>>(xbh, rp, cw, wh1, b1, nullptr, xah, dk[2][0], dk[2][1], n);
  k_conv<32, false, false, false><<<bc, 256, 0, stream>>>(xah, rp, cw, wh2, b2, out, nullptr, 0u, 0u, n);
}

// Round 8
// 232.646 us; speedup vs baseline: 1.6517x; 1.2484x over previous
//
#include <hip/hip_runtime.h>
#include <stdint.h>

typedef _Float16 half8 __attribute__((ext_vector_type(8)));
typedef float float4v __attribute__((ext_vector_type(4)));

__host__ __device__ inline void tf2x32(uint32_t k0, uint32_t k1,
                                       uint32_t x0, uint32_t x1,
                                       uint32_t* o0, uint32_t* o1) {
  const uint32_t ks2 = k0 ^ k1 ^ 0x1BD11BDAu;
#define ROTL(v, s) (((v) << (s)) | ((v) >> (32 - (s))))
#define RND(r) do { x0 += x1; x1 = ROTL(x1, r); x1 ^= x0; } while (0)
  x0 += k0; x1 += k1;
  RND(13); RND(15); RND(26); RND(6);
  x0 += k1; x1 += ks2 + 1u;
  RND(17); RND(29); RND(16); RND(24);
  x0 += ks2; x1 += k0 + 2u;
  RND(13); RND(15); RND(26); RND(6);
  x0 += k0; x1 += k1 + 3u;
  RND(17); RND(29); RND(16); RND(24);
  x0 += k1; x1 += ks2 + 4u;
  RND(13); RND(15); RND(26); RND(6);
  x0 += ks2; x1 += k0 + 5u;
  *o0 = x0; *o1 = x1;
#undef RND
#undef ROTL
}

__device__ inline bool drop_keep(uint32_t k0, uint32_t k1, uint32_t idx) {
  uint32_t o0, o1;
  tf2x32(k0, k1, 0u, idx, &o0, &o1);
  uint32_t bits = o0 ^ o1;
  float u = __uint_as_float((bits >> 9) | 0x3f800000u) - 1.0f;
  return u < 0.4f;
}

// Single-pass slotted-CSR fill: cs[r*64 + cnt[r]++] = col (u16).
// First 80 blocks also convert W0/W1/W2 to f16 W^T layout wh[o][k].
__global__ void k_fill2(const int* __restrict__ row, const int* __restrict__ col,
                        int* __restrict__ cnt, uint16_t* __restrict__ cs, int e,
                        const float* __restrict__ W0, const float* __restrict__ W1,
                        const float* __restrict__ W2, _Float16* __restrict__ wh) {
  int i = blockIdx.x * 256 + threadIdx.x;
  if (blockIdx.x < 80) {
    int d = i;                       // 0..20479
    if (d < 8192) {
      int o = d >> 7, k = d & 127;
      wh[d] = (_Float16)W0[k * 64 + o];
    } else if (d < 16384) {
      int d1 = d - 8192, o = d1 >> 7, k = d1 & 127;
      wh[d] = (_Float16)W1[k * 64 + o];
    } else if (d < 20480) {
      int d2 = d - 16384, o = d2 >> 7, k = d2 & 127;
      wh[d] = (_Float16)W2[k * 32 + o];
    }
  }
  if (i < e) {
    int r = row[i];
    int pos = atomicAdd(&cnt[r], 1);
    if (pos < 64) cs[(r << 6) + pos] = (uint16_t)col[i];
  }
}

// After fill: layer-0 dropout (fp32 -> f16 y and dis-scaled ys), dis[r],
// pad each row's cs slots to a multiple of 8 with dummy index n (zero row),
// zero the dummy rows of both ys buffers.
__global__ void k_drop(const float* __restrict__ x, const int* __restrict__ cnt,
                       uint16_t* __restrict__ cs, float* __restrict__ dis,
                       _Float16* __restrict__ y, _Float16* __restrict__ ys,
                       _Float16* __restrict__ ysb, uint32_t k0, uint32_t k1,
                       int n, int nd) {
  int i = blockIdx.x * 256 + threadIdx.x;
  if (i < 64) {                        // zero dummy gather rows (index n)
    ys[((size_t)n << 6) + i]  = (_Float16)0.f;
    ysb[((size_t)n << 6) + i] = (_Float16)0.f;
  }
  if (i < nd) {
    const int r = i >> 6;
    const int t = i & 63;
    const int d = cnt[r];
    const float dis_r = (d > 0) ? rsqrtf((float)d) : 0.0f;
    float v = drop_keep(k0, k1, (uint32_t)i) ? x[i] * 2.5f : 0.0f;
    y[i]  = (_Float16)v;
    ys[i] = (_Float16)(dis_r * v);
    if (t == 0) dis[r] = dis_r;
    const int cn = d < 64 ? d : 64;
    const int rnd = (cn + 7) & ~7;
    if (t >= cn && t < rnd) cs[(r << 6) + t] = (uint16_t)n;  // pad slot
  }
}

// Fused conv. Block = 256 threads = 4 waves, R = 16 rows. Activations f16.
// Phase 1: per-wave gather p_r = -dis_r * sum_e ys[c_e] over padded slots
//          (8-deep, NO masking: pad slots hit the zeroed dummy row n).
// Phase 2: MFMA 16x16x32_f16; A = [y_r | p_r] tile from LDS, B = global W^T.
// Phase 3: epilogue: +bias, relu, next-layer dropout; store y (and dis-scaled
//          ys for the next gather) as f16, or fp32 final output.
template<int COUT, bool RELU, bool DROPN, bool WBF>
__global__ __launch_bounds__(256, 8) void k_conv(
    const _Float16* __restrict__ yg, const _Float16* __restrict__ ysg,
    const int* __restrict__ cnt, const uint16_t* __restrict__ cs,
    const float* __restrict__ dis, const _Float16* __restrict__ wt,
    const float* __restrict__ b, float* __restrict__ outf,
    _Float16* __restrict__ outb, _Float16* __restrict__ outs,
    uint32_t nk0, uint32_t nk1, int n) {
  constexpr int R  = 16;
  constexpr int TS = 136;
  __shared__ __align__(16) _Float16 xp[R][TS];

  const int wave = threadIdx.x >> 6;
  const int t    = threadIdx.x & 63;
  const int row0 = blockIdx.x * R;

  // ---- Phase 1: gather ----
  for (int i = 0; i < 4; ++i) {
    const int rl = wave * 4 + i;
    const int r  = row0 + rl;
    if (r < n) {
      float acc = 0.0f;
      const int d   = cnt[r];
      const int cn  = d < 64 ? d : 64;
      const int rnd = (cn + 7) & ~7;            // padded slot count
      const int base = r << 6;
      for (int j = 0; j < rnd; j += 8) {
        const uint4 cc = *(const uint4*)&cs[base + j];  // 8 u16 indices
        uint32_t c[8];
        c[0] = cc.x & 0xffffu; c[1] = cc.x >> 16;
        c[2] = cc.y & 0xffffu; c[3] = cc.y >> 16;
        c[4] = cc.z & 0xffffu; c[5] = cc.z >> 16;
        c[6] = cc.w & 0xffffu; c[7] = cc.w >> 16;
        _Float16 xv[8];
        #pragma unroll
        for (int k = 0; k < 8; ++k) xv[k] = ysg[(c[k] << 6) + t];
        #pragma unroll
        for (int k = 0; k < 8; ++k) acc += (float)xv[k];
      }
      xp[rl][t]      = yg[(uint32_t)(r << 6) + t];
      xp[rl][64 + t] = (_Float16)(-dis[r] * acc);
    }
  }
  __syncthreads();

  // ---- Phase 2: MFMA (B fragments from global W^T) ----
  constexpr int NW = COUT / 16;
  const int nn   = t & 15;
  const int quad = t >> 4;
  if (wave < NW) {
    const int colg = wave * 16 + nn;
    float4v acc = {0.f, 0.f, 0.f, 0.f};
    #pragma unroll
    for (int ks = 0; ks < 4; ++ks) {
      half8 a  = *(const half8*)&xp[nn][quad * 8 + 32 * ks];
      half8 bb = *(const half8*)&wt[(size_t)colg * 128 + quad * 8 + 32 * ks];
      acc = __builtin_amdgcn_mfma_f32_16x16x32_f16(a, bb, acc, 0, 0, 0);
    }
    // ---- Phase 3: epilogue ----
    const float bias = b[colg];
    #pragma unroll
    for (int rg = 0; rg < 4; ++rg) {
      const int rl = quad * 4 + rg;
      const int rr = row0 + rl;
      if (rr < n) {
        float v = acc[rg] + bias;
        if (RELU) v = fmaxf(v, 0.0f);
        if (DROPN) {
          if (drop_keep(nk0, nk1, (uint32_t)(rr * 64 + colg))) v *= 2.5f;
          else v = 0.0f;
        }
        if (WBF) {
          outb[(size_t)rr * COUT + colg] = (_Float16)v;
          outs[(size_t)rr * COUT + colg] = (_Float16)(dis[rr] * v);
        } else {
          outf[(size_t)rr * COUT + colg] = v;
        }
      }
    }
  }
}

extern "C" void kernel_launch(void* const* d_in, const int* in_sizes, int n_in,
                              void* d_out, int out_size, void* d_ws, size_t ws_size,
                              hipStream_t stream) {
  const float* x   = (const float*)d_in[0];
  const int*   ei  = (const int*)d_in[1];
  const float* W0  = (const float*)d_in[2];
  const float* b0  = (const float*)d_in[3];
  const float* W1f = (const float*)d_in[4];
  const float* b1  = (const float*)d_in[5];
  const float* W2  = (const float*)d_in[6];
  const float* b2  = (const float*)d_in[7];
  float* out = (float*)d_out;

  const int n = in_sizes[0] / 64;   // 50000
  const int e = in_sizes[1] / 2;    // 800000
  const int* row = ei;
  const int* col = ei + e;

  size_t off = 0;
  auto carve = [&](size_t elems) {   // elems in int32 units, 1KB-aligned
    size_t o = off;
    off += (elems + 255) & ~(size_t)255;
    return o;
  };
  int* base = (int*)d_ws;
  int*      cnt = base + carve(n);
  float*    dis = (float*)(base + carve(n));
  uint16_t* cs  = (uint16_t*)(base + carve((size_t)n * 32));       // n*64 u16
  _Float16* ya  = (_Float16*)(base + carve((size_t)n * 32));       // n*64 f16
  _Float16* ysa = (_Float16*)(base + carve((size_t)(n + 1) * 32)); // (n+1)*64 f16
  _Float16* yb  = (_Float16*)(base + carve((size_t)n * 32));
  _Float16* ysb = (_Float16*)(base + carve((size_t)(n + 1) * 32));
  _Float16* wh  = (_Float16*)(base + carve(10240));                // 20480 f16
  (void)ws_size;
  _Float16* wh0 = wh;            // [64][128]
  _Float16* wh1 = wh + 8192;     // [64][128]
  _Float16* wh2 = wh + 16384;    // [32][128]

  // dropout keys: fold_in(jax.random.key(1), i) = threefry2x32([0,1],[0,i])
  uint32_t dk[3][2];
  for (uint32_t i = 0; i < 3; ++i) tf2x32(0u, 1u, 0u, i, &dk[i][0], &dk[i][1]);

  hipMemsetAsync(cnt, 0, (size_t)n * 4, stream);

  const int be = (e + 255) / 256;        // 3125
  const int bd = ((n * 64) + 255) / 256; // 12500
  const int bc = (n + 15) / 16;          // 3125

  k_fill2<<<be, 256, 0, stream>>>(row, col, cnt, cs, e, W0, W1f, W2, wh);
  k_drop<<<bd, 256, 0, stream>>>(x, cnt, cs, dis, ya, ysa, ysb,
                                 dk[0][0], dk[0][1], n, n * 64);

  k_conv<64, true,  true,  true ><<<bc, 256, 0, stream>>>(
      ya, ysa, cnt, cs, dis, wh0, b0, nullptr, yb, ysb, dk[1][0], dk[1][1], n);
  k_conv<64, true,  true,  true ><<<bc, 256, 0, stream>>>(
      yb, ysb, cnt, cs, dis, wh1, b1, nullptr, ya, ysa, dk[2][0], dk[2][1], n);
  k_conv<32, false, false, false><<<bc, 256, 0, stream>>>(
      ya, ysa, cnt, cs, dis, wh2, b2, out, nullptr, nullptr, 0u, 0u, n);
}

// Round 9
// 211.188 us; speedup vs baseline: 1.8195x; 1.1016x over previous
//
#include <hip/hip_runtime.h>
#include <stdint.h>

typedef _Float16 half8 __attribute__((ext_vector_type(8)));
typedef float float4v __attribute__((ext_vector_type(4)));

__host__ __device__ inline void tf2x32(uint32_t k0, uint32_t k1,
                                       uint32_t x0, uint32_t x1,
                                       uint32_t* o0, uint32_t* o1) {
  const uint32_t ks2 = k0 ^ k1 ^ 0x1BD11BDAu;
#define ROTL(v, s) (((v) << (s)) | ((v) >> (32 - (s))))
#define RND(r) do { x0 += x1; x1 = ROTL(x1, r); x1 ^= x0; } while (0)
  x0 += k0; x1 += k1;
  RND(13); RND(15); RND(26); RND(6);
  x0 += k1; x1 += ks2 + 1u;
  RND(17); RND(29); RND(16); RND(24);
  x0 += ks2; x1 += k0 + 2u;
  RND(13); RND(15); RND(26); RND(6);
  x0 += k0; x1 += k1 + 3u;
  RND(17); RND(29); RND(16); RND(24);
  x0 += k1; x1 += ks2 + 4u;
  RND(13); RND(15); RND(26); RND(6);
  x0 += ks2; x1 += k0 + 5u;
  *o0 = x0; *o1 = x1;
#undef RND
#undef ROTL
}

__device__ inline bool drop_keep(uint32_t k0, uint32_t k1, uint32_t idx) {
  uint32_t o0, o1;
  tf2x32(k0, k1, 0u, idx, &o0, &o1);
  uint32_t bits = o0 ^ o1;
  float u = __uint_as_float((bits >> 9) | 0x3f800000u) - 1.0f;
  return u < 0.4f;
}

// XCD-owned slotted-CSR fill. Grid = 8 * nchunks. Block b: chunk = b>>3,
// owner slice = b&7 (round-robins over XCDs). Only edges whose row falls in
// the owner's contiguous range are handled -> every cs line + cnt atomic is
// single-XCD (1 writeback copy instead of ~5-7). Edge list re-read 8x is
// L3-absorbed. Correct for ANY block->XCD mapping (each edge processed by
// exactly one block per chunk).
__global__ void k_fill2(const int* __restrict__ row, const int* __restrict__ col,
                        int* __restrict__ cnt, uint16_t* __restrict__ cs,
                        int e, int rows_per_xcd) {
  const int owner = blockIdx.x & 7;
  const int i = (blockIdx.x >> 3) * 256 + threadIdx.x;
  if (i < e) {
    int r = row[i];
    if (r / rows_per_xcd == owner) {
      int pos = atomicAdd(&cnt[r], 1);
      if (pos < 64) cs[(r << 6) + pos] = (uint16_t)col[i];
    }
  }
}

// After fill: layer-0 dropout (fp32 -> f16 y and dis-scaled ys), dis[r],
// pad each row's cs slots to a multiple of 8 with dummy index n (zero row),
// zero the dummy rows, and (first 80 blocks) convert W0/W1/W2 to f16 W^T.
__global__ void k_drop(const float* __restrict__ x, const int* __restrict__ cnt,
                       uint16_t* __restrict__ cs, float* __restrict__ dis,
                       _Float16* __restrict__ y, _Float16* __restrict__ ys,
                       _Float16* __restrict__ ysb, uint32_t k0, uint32_t k1,
                       int n, int nd,
                       const float* __restrict__ W0, const float* __restrict__ W1,
                       const float* __restrict__ W2, _Float16* __restrict__ wh) {
  int i = blockIdx.x * 256 + threadIdx.x;
  if (i < 20480) {
    int d = i;
    if (d < 8192) {
      int o = d >> 7, k = d & 127;
      wh[d] = (_Float16)W0[k * 64 + o];
    } else if (d < 16384) {
      int d1 = d - 8192, o = d1 >> 7, k = d1 & 127;
      wh[d] = (_Float16)W1[k * 64 + o];
    } else {
      int d2 = d - 16384, o = d2 >> 7, k = d2 & 127;
      wh[d] = (_Float16)W2[k * 32 + o];
    }
  }
  if (i < 64) {                        // zero dummy gather rows (index n)
    ys[((size_t)n << 6) + i]  = (_Float16)0.f;
    ysb[((size_t)n << 6) + i] = (_Float16)0.f;
  }
  if (i < nd) {
    const int r = i >> 6;
    const int t = i & 63;
    const int d = cnt[r];
    const float dis_r = (d > 0) ? rsqrtf((float)d) : 0.0f;
    float v = drop_keep(k0, k1, (uint32_t)i) ? x[i] * 2.5f : 0.0f;
    y[i]  = (_Float16)v;
    ys[i] = (_Float16)(dis_r * v);
    if (t == 0) dis[r] = dis_r;
    const int cn = d < 64 ? d : 64;
    const int rnd = (cn + 7) & ~7;
    if (t >= cn && t < rnd) cs[(r << 6) + t] = (uint16_t)n;  // pad slot
  }
}

// Fused conv. Block = 256 threads = 4 waves, R = 16 rows. Activations f16.
// Phase 1: per-wave gather p_r = -dis_r * sum_e ys[c_e] over padded slots
//          (16-deep batches + optional 8-tail, NO masking: pads hit zero row).
// Phase 2: MFMA 16x16x32_f16; A = [y_r | p_r] tile from LDS, B = global W^T.
// Phase 3: epilogue: +bias, relu, next-layer dropout; dual store y / ys.
template<int COUT, bool RELU, bool DROPN, bool WBF>
__global__ __launch_bounds__(256, 8) void k_conv(
    const _Float16* __restrict__ yg, const _Float16* __restrict__ ysg,
    const int* __restrict__ cnt, const uint16_t* __restrict__ cs,
    const float* __restrict__ dis, const _Float16* __restrict__ wt,
    const float* __restrict__ b, float* __restrict__ outf,
    _Float16* __restrict__ outb, _Float16* __restrict__ outs,
    uint32_t nk0, uint32_t nk1, int n) {
  constexpr int R  = 16;
  constexpr int TS = 136;
  __shared__ __align__(16) _Float16 xp[R][TS];

  const int wave = threadIdx.x >> 6;
  const int t    = threadIdx.x & 63;
  const int row0 = blockIdx.x * R;

  // ---- Phase 1: gather ----
  for (int i = 0; i < 4; ++i) {
    const int rl = wave * 4 + i;
    const int r  = row0 + rl;
    if (r < n) {
      float acc = 0.0f;
      const int d   = cnt[r];
      const int cn  = d < 64 ? d : 64;
      const int rnd = (cn + 7) & ~7;            // padded slot count
      const int base = r << 6;
      int j = 0;
      for (; j + 16 <= rnd; j += 16) {          // 16-deep batches
        const uint4 c0 = *(const uint4*)&cs[base + j];
        const uint4 c1 = *(const uint4*)&cs[base + j + 8];
        uint32_t c[16];
        c[0]  = c0.x & 0xffffu; c[1]  = c0.x >> 16;
        c[2]  = c0.y & 0xffffu; c[3]  = c0.y >> 16;
        c[4]  = c0.z & 0xffffu; c[5]  = c0.z >> 16;
        c[6]  = c0.w & 0xffffu; c[7]  = c0.w >> 16;
        c[8]  = c1.x & 0xffffu; c[9]  = c1.x >> 16;
        c[10] = c1.y & 0xffffu; c[11] = c1.y >> 16;
        c[12] = c1.z & 0xffffu; c[13] = c1.z >> 16;
        c[14] = c1.w & 0xffffu; c[15] = c1.w >> 16;
        _Float16 xv[16];
        #pragma unroll
        for (int k = 0; k < 16; ++k) xv[k] = ysg[(c[k] << 6) + t];
        #pragma unroll
        for (int k = 0; k < 16; ++k) acc += (float)xv[k];
      }
      if (j < rnd) {                            // one 8-deep tail batch
        const uint4 cc = *(const uint4*)&cs[base + j];
        uint32_t c[8];
        c[0] = cc.x & 0xffffu; c[1] = cc.x >> 16;
        c[2] = cc.y & 0xffffu; c[3] = cc.y >> 16;
        c[4] = cc.z & 0xffffu; c[5] = cc.z >> 16;
        c[6] = cc.w & 0xffffu; c[7] = cc.w >> 16;
        _Float16 xv[8];
        #pragma unroll
        for (int k = 0; k < 8; ++k) xv[k] = ysg[(c[k] << 6) + t];
        #pragma unroll
        for (int k = 0; k < 8; ++k) acc += (float)xv[k];
      }
      xp[rl][t]      = yg[(uint32_t)(r << 6) + t];
      xp[rl][64 + t] = (_Float16)(-dis[r] * acc);
    }
  }
  __syncthreads();

  // ---- Phase 2: MFMA (B fragments from global W^T) ----
  constexpr int NW = COUT / 16;
  const int nn   = t & 15;
  const int quad = t >> 4;
  if (wave < NW) {
    const int colg = wave * 16 + nn;
    float4v acc = {0.f, 0.f, 0.f, 0.f};
    #pragma unroll
    for (int ks = 0; ks < 4; ++ks) {
      half8 a  = *(const half8*)&xp[nn][quad * 8 + 32 * ks];
      half8 bb = *(const half8*)&wt[(size_t)colg * 128 + quad * 8 + 32 * ks];
      acc = __builtin_amdgcn_mfma_f32_16x16x32_f16(a, bb, acc, 0, 0, 0);
    }
    // ---- Phase 3: epilogue ----
    const float bias = b[colg];
    #pragma unroll
    for (int rg = 0; rg < 4; ++rg) {
      const int rl = quad * 4 + rg;
      const int rr = row0 + rl;
      if (rr < n) {
        float v = acc[rg] + bias;
        if (RELU) v = fmaxf(v, 0.0f);
        if (DROPN) {
          if (drop_keep(nk0, nk1, (uint32_t)(rr * 64 + colg))) v *= 2.5f;
          else v = 0.0f;
        }
        if (WBF) {
          outb[(size_t)rr * COUT + colg] = (_Float16)v;
          outs[(size_t)rr * COUT + colg] = (_Float16)(dis[rr] * v);
        } else {
          outf[(size_t)rr * COUT + colg] = v;
        }
      }
    }
  }
}

extern "C" void kernel_launch(void* const* d_in, const int* in_sizes, int n_in,
                              void* d_out, int out_size, void* d_ws, size_t ws_size,
                              hipStream_t stream) {
  const float* x   = (const float*)d_in[0];
  const int*   ei  = (const int*)d_in[1];
  const float* W0  = (const float*)d_in[2];
  const float* b0  = (const float*)d_in[3];
  const float* W1f = (const float*)d_in[4];
  const float* b1  = (const float*)d_in[5];
  const float* W2  = (const float*)d_in[6];
  const float* b2  = (const float*)d_in[7];
  float* out = (float*)d_out;

  const int n = in_sizes[0] / 64;   // 50000
  const int e = in_sizes[1] / 2;    // 800000
  const int* row = ei;
  const int* col = ei + e;

  size_t off = 0;
  auto carve = [&](size_t elems) {   // elems in int32 units, 1KB-aligned
    size_t o = off;
    off += (elems + 255) & ~(size_t)255;
    return o;
  };
  int* base = (int*)d_ws;
  int*      cnt = base + carve(n);
  float*    dis = (float*)(base + carve(n));
  uint16_t* cs  = (uint16_t*)(base + carve((size_t)n * 32));       // n*64 u16
  _Float16* ya  = (_Float16*)(base + carve((size_t)n * 32));       // n*64 f16
  _Float16* ysa = (_Float16*)(base + carve((size_t)(n + 1) * 32)); // (n+1)*64 f16
  _Float16* yb  = (_Float16*)(base + carve((size_t)n * 32));
  _Float16* ysb = (_Float16*)(base + carve((size_t)(n + 1) * 32));
  _Float16* wh  = (_Float16*)(base + carve(10240));                // 20480 f16
  (void)ws_size;
  _Float16* wh0 = wh;            // [64][128]
  _Float16* wh1 = wh + 8192;     // [64][128]
  _Float16* wh2 = wh + 16384;    // [32][128]

  // dropout keys: fold_in(jax.random.key(1), i) = threefry2x32([0,1],[0,i])
  uint32_t dk[3][2];
  for (uint32_t i = 0; i < 3; ++i) tf2x32(0u, 1u, 0u, i, &dk[i][0], &dk[i][1]);

  hipMemsetAsync(cnt, 0, (size_t)n * 4, stream);

  const int nchunk = (e + 255) / 256;    // 3125
  const int bd = ((n * 64) + 255) / 256; // 12500
  const int bc = (n + 15) / 16;          // 3125
  const int rpx = (n + 7) / 8;           // rows per XCD slice (6250)

  k_fill2<<<nchunk * 8, 256, 0, stream>>>(row, col, cnt, cs, e, rpx);
  k_drop<<<bd, 256, 0, stream>>>(x, cnt, cs, dis, ya, ysa, ysb,
                                 dk[0][0], dk[0][1], n, n * 64,
                                 W0, W1f, W2, wh);

  k_conv<64, true,  true,  true ><<<bc, 256, 0, stream>>>(
      ya, ysa, cnt, cs, dis, wh0, b0, nullptr, yb, ysb, dk[1][0], dk[1][1], n);
  k_conv<64, true,  true,  true ><<<bc, 256, 0, stream>>>(
      yb, ysb, cnt, cs, dis, wh1, b1, nullptr, ya, ysa, dk[2][0], dk[2][1], n);
  k_conv<32, false, false, false><<<bc, 256, 0, stream>>>(
      ya, ysa, cnt, cs, dis, wh2, b2, out, nullptr, nullptr, 0u, 0u, n);
}